// Round 1
// baseline (1322.388 us; speedup 1.0000x reference)
//
#include <hip/hip_runtime.h>
#include <hip/hip_bf16.h>
#include <stdint.h>

#define N_NODES 100000
#define N_EDGES 3200000
#define D_FEAT 256

typedef __attribute__((ext_vector_type(8))) short short8;
typedef __attribute__((ext_vector_type(4))) float float4v;

__device__ inline unsigned short f2bf(float f) {
    union { float f; unsigned u; } v; v.f = f;
    unsigned u = v.u;
    u += 0x7FFF + ((u >> 16) & 1);   // round-to-nearest-even
    return (unsigned short)(u >> 16);
}

// ---- CSR build ----------------------------------------------------------

__global__ void hist_kernel(const int* __restrict__ erow, int* __restrict__ counts) {
    int i = blockIdx.x * blockDim.x + threadIdx.x;   // grid sized exactly N_EDGES
    atomicAdd(&counts[erow[i]], 1);
}

// Single-block exclusive scan over counts (stored in row_start), writes
// row_start (exclusive prefix) + cursor (copy) + row_start[N]=E.
__global__ void scan_kernel(int* __restrict__ row_start, int* __restrict__ cursor) {
    const int T = 1024;
    const int SEG = (N_NODES + T - 1) / T;  // 98
    int t = threadIdx.x;
    __shared__ int sums[T];
    int base = t * SEG;
    int s = 0;
    for (int j = 0; j < SEG; ++j) {
        int i = base + j;
        if (i < N_NODES) s += row_start[i];
    }
    sums[t] = s;
    __syncthreads();
    for (int off = 1; off < T; off <<= 1) {
        int x = (t >= off) ? sums[t - off] : 0;
        __syncthreads();
        sums[t] += x;
        __syncthreads();
    }
    int run = sums[t] - s;                  // exclusive prefix of this segment
    for (int j = 0; j < SEG; ++j) {
        int i = base + j;
        if (i < N_NODES) {
            int c = row_start[i];
            row_start[i] = run;
            cursor[i] = run;
            run += c;
        }
    }
    if (t == T - 1) row_start[N_NODES] = run;   // == N_EDGES
}

__global__ void scatter_kernel(const int* __restrict__ erow, const int* __restrict__ ecol,
                               const float* __restrict__ eval,
                               int* __restrict__ cursor,
                               int* __restrict__ csr_col, float* __restrict__ csr_val) {
    int i = blockIdx.x * blockDim.x + threadIdx.x;   // grid sized exactly N_EDGES
    int r = erow[i];
    int pos = atomicAdd(&cursor[r], 1);
    csr_col[pos] = ecol[i];
    csr_val[pos] = eval[i];
}

// ---- SpMM: one wave per row ---------------------------------------------

__global__ __launch_bounds__(256) void spmm_kernel(
        const float4* __restrict__ x4,            // [N][64] float4
        const int* __restrict__ row_start,
        const int* __restrict__ csr_col, const float* __restrict__ csr_val,
        ushort* __restrict__ agg_bf) {            // [N][256] bf16
    int wave = (blockIdx.x * blockDim.x + threadIdx.x) >> 6;  // row index
    int lane = threadIdx.x & 63;
    if (wave >= N_NODES) return;
    int start = row_start[wave];
    int end   = row_start[wave + 1];
    float4v acc = {0.f, 0.f, 0.f, 0.f};
    for (int e = start; e < end; ++e) {
        int c   = csr_col[e];
        float v = csr_val[e];
        float4 xv = x4[c * 64 + lane];
        acc[0] += v * xv.x;
        acc[1] += v * xv.y;
        acc[2] += v * xv.z;
        acc[3] += v * xv.w;
    }
    ushort4 o;
    o.x = f2bf(acc[0]); o.y = f2bf(acc[1]);
    o.z = f2bf(acc[2]); o.w = f2bf(acc[3]);
    ((ushort4*)agg_bf)[wave * 64 + lane] = o;
}

// ---- W fp32 -> bf16 ------------------------------------------------------

__global__ void wconv_kernel(const float* __restrict__ W, ushort* __restrict__ Wbf) {
    int i = blockIdx.x * 256 + threadIdx.x;   // 256 blocks x 256 = 65536
    Wbf[i] = f2bf(W[i]);
}

// ---- GEMM: out[i][n] = sum_k agg[i][k] * W[n][k] (bf16 MFMA) ------------

__global__ __launch_bounds__(256) void gemm_kernel(
        const ushort* __restrict__ Abf,   // [N][256] bf16
        const ushort* __restrict__ Wbf,   // [256][256] bf16, n-major (k contiguous)
        float* __restrict__ out) {        // [N][256] fp32
    int w    = threadIdx.x >> 6;          // wave 0..3 -> col group of 64
    int lane = threadIdx.x & 63;
    int quad = lane >> 4;
    int l16  = lane & 15;
    int rt   = blockIdx.x * 16;           // 6250 blocks, M=100000=16*6250

    float4v acc[4];
    #pragma unroll
    for (int i = 0; i < 4; ++i) acc[i] = (float4v){0.f, 0.f, 0.f, 0.f};

    #pragma unroll
    for (int k0 = 0; k0 < 256; k0 += 32) {
        short8 a = *(const short8*)&Abf[(rt + l16) * 256 + k0 + quad * 8];
        #pragma unroll
        for (int nt = 0; nt < 4; ++nt) {
            int n = w * 64 + nt * 16 + l16;
            short8 b = *(const short8*)&Wbf[n * 256 + k0 + quad * 8];
            acc[nt] = __builtin_amdgcn_mfma_f32_16x16x32_bf16(a, b, acc[nt], 0, 0, 0);
        }
    }
    #pragma unroll
    for (int nt = 0; nt < 4; ++nt) {
        int n = w * 64 + nt * 16 + l16;
        #pragma unroll
        for (int r = 0; r < 4; ++r) {
            int row = rt + quad * 4 + r;   // C/D layout: col=lane&15, row=quad*4+reg
            out[row * 256 + n] = acc[nt][r];
        }
    }
}

// ---- launch --------------------------------------------------------------

extern "C" void kernel_launch(void* const* d_in, const int* in_sizes, int n_in,
                              void* d_out, int out_size, void* d_ws, size_t ws_size,
                              hipStream_t stream) {
    const float* x    = (const float*)d_in[0];
    const int*   erow = (const int*)d_in[1];
    const int*   ecol = (const int*)d_in[2];
    const float* eval = (const float*)d_in[3];
    const float* W    = (const float*)d_in[4];
    float* out = (float*)d_out;

    char* ws = (char*)d_ws;
    size_t off = 0;
    int* row_start = (int*)(ws + off);            off += ((size_t)(N_NODES + 1) * 4 + 255) & ~255ull;
    int* cursor    = (int*)(ws + off);            off += ((size_t)N_NODES * 4 + 255) & ~255ull;
    int* csr_col   = (int*)(ws + off);            off += (size_t)N_EDGES * 4;
    float* csr_val = (float*)(ws + off);          off += (size_t)N_EDGES * 4;
    ushort* Wbf    = (ushort*)(ws + off);         off += (size_t)D_FEAT * D_FEAT * 2;
    ushort* agg_bf = (ushort*)(ws + off);         off += (size_t)N_NODES * D_FEAT * 2;

    hipMemsetAsync(row_start, 0, (N_NODES + 1) * sizeof(int), stream);
    hist_kernel<<<N_EDGES / 256, 256, 0, stream>>>(erow, row_start);
    scan_kernel<<<1, 1024, 0, stream>>>(row_start, cursor);
    scatter_kernel<<<N_EDGES / 256, 256, 0, stream>>>(erow, ecol, eval, cursor, csr_col, csr_val);
    wconv_kernel<<<(D_FEAT * D_FEAT) / 256, 256, 0, stream>>>(W, Wbf);
    spmm_kernel<<<(N_NODES + 3) / 4, 256, 0, stream>>>((const float4*)x, row_start, csr_col, csr_val, agg_bf);
    gemm_kernel<<<N_NODES / 16, 256, 0, stream>>>(agg_bf, Wbf, out);
}

// Round 2
// 894.667 us; speedup vs baseline: 1.4781x; 1.4781x over previous
//
#include <hip/hip_runtime.h>
#include <hip/hip_bf16.h>
#include <stdint.h>

#define N_NODES 100000
#define N_EDGES 3200000
#define D_FEAT 256
#define NBLK 391   // ceil(N_NODES / 256)

typedef __attribute__((ext_vector_type(8))) short short8;
typedef __attribute__((ext_vector_type(8))) ushort ushort8;
typedef __attribute__((ext_vector_type(4))) float float4v;

__device__ inline unsigned short f2bf(float f) {
    union { float f; unsigned u; } v; v.f = f;
    unsigned u = v.u;
    u += 0x7FFF + ((u >> 16) & 1);   // round-to-nearest-even
    return (unsigned short)(u >> 16);
}
__device__ inline float bf2f(unsigned short u) {
    union { unsigned u; float f; } v; v.u = (unsigned)u << 16;
    return v.f;
}

// ---- x fp32 -> bf16 (streaming) -----------------------------------------
__global__ __launch_bounds__(256) void xconv_kernel(const float4* __restrict__ x4,
                                                    ushort4* __restrict__ xbf4) {
    int i = blockIdx.x * 256 + threadIdx.x;   // 25000 blocks, exact
    float4 v = x4[i];
    ushort4 o;
    o.x = f2bf(v.x); o.y = f2bf(v.y); o.z = f2bf(v.z); o.w = f2bf(v.w);
    xbf4[i] = o;
}

// ---- CSR build ----------------------------------------------------------

__global__ void hist_kernel(const int* __restrict__ erow, int* __restrict__ counts) {
    int i = blockIdx.x * blockDim.x + threadIdx.x;   // grid exactly N_EDGES
    atomicAdd(&counts[erow[i]], 1);
}

__global__ __launch_bounds__(256) void scan_pass1(const int* __restrict__ counts,
                                                  int* __restrict__ bsum) {
    __shared__ int s[256];
    int i = blockIdx.x * 256 + threadIdx.x;
    int t = threadIdx.x;
    s[t] = (i < N_NODES) ? counts[i] : 0;
    __syncthreads();
    for (int o = 128; o > 0; o >>= 1) {
        if (t < o) s[t] += s[t + o];
        __syncthreads();
    }
    if (t == 0) bsum[blockIdx.x] = s[0];
}

__global__ __launch_bounds__(512) void scan_pass2(const int* __restrict__ bsum,
                                                  int* __restrict__ bbase) {
    __shared__ int s[512];
    int t = threadIdx.x;
    int v = (t < NBLK) ? bsum[t] : 0;
    s[t] = v;
    __syncthreads();
    for (int o = 1; o < 512; o <<= 1) {
        int x = (t >= o) ? s[t - o] : 0;
        __syncthreads();
        s[t] += x;
        __syncthreads();
    }
    if (t < NBLK) bbase[t] = s[t] - v;   // exclusive
}

__global__ __launch_bounds__(256) void scan_pass3(const int* __restrict__ counts,
                                                  const int* __restrict__ bbase,
                                                  int* __restrict__ row_start,
                                                  int* __restrict__ cursor) {
    __shared__ int s[256];
    int i = blockIdx.x * 256 + threadIdx.x;
    int t = threadIdx.x;
    int v = (i < N_NODES) ? counts[i] : 0;
    s[t] = v;
    __syncthreads();
    for (int o = 1; o < 256; o <<= 1) {
        int x = (t >= o) ? s[t - o] : 0;
        __syncthreads();
        s[t] += x;
        __syncthreads();
    }
    int excl = bbase[blockIdx.x] + s[t] - v;
    if (i < N_NODES) { row_start[i] = excl; cursor[i] = excl; }
    if (i == N_NODES - 1) row_start[N_NODES] = excl + v;
}

__global__ void scatter_kernel(const int* __restrict__ erow, const int* __restrict__ ecol,
                               const float* __restrict__ eval,
                               int* __restrict__ cursor,
                               uint2* __restrict__ csr_cv) {
    int i = blockIdx.x * blockDim.x + threadIdx.x;   // grid exactly N_EDGES
    int r = erow[i];
    int pos = atomicAdd(&cursor[r], 1);
    uint2 cv;
    cv.x = (unsigned)ecol[i];
    union { float f; unsigned u; } w; w.f = eval[i];
    cv.y = w.u;
    csr_cv[pos] = cv;
}

// ---- SpMM: one wave per row, half-wave per edge -------------------------
// Lanes 0-31 handle even-offset edges, lanes 32-63 odd; each half-lane loads
// 8 bf16 features (16B). Cross-half combine via shfl_xor(32).
__global__ __launch_bounds__(256) void spmm_kernel(
        const ushort* __restrict__ xbf,           // [N][256] bf16
        const int* __restrict__ row_start,
        const uint2* __restrict__ csr_cv,
        ushort* __restrict__ agg_bf) {            // [N][256] bf16
    int row  = (blockIdx.x * blockDim.x + threadIdx.x) >> 6;
    int lane = threadIdx.x & 63;
    int half = lane >> 5;
    int hl   = lane & 31;
    if (row >= N_NODES) return;
    int start = row_start[row];
    int end   = row_start[row + 1];
    float acc[8] = {0.f, 0.f, 0.f, 0.f, 0.f, 0.f, 0.f, 0.f};
    int e = start + half;
    for (; e + 2 < end; e += 4) {       // 2 edges per half-wave per iter
        uint2 cv0 = csr_cv[e];
        uint2 cv1 = csr_cv[e + 2];
        ushort8 v0 = *(const ushort8*)&xbf[(size_t)cv0.x * 256 + hl * 8];
        ushort8 v1 = *(const ushort8*)&xbf[(size_t)cv1.x * 256 + hl * 8];
        union { unsigned u; float f; } w0, w1;
        w0.u = cv0.y; w1.u = cv1.y;
        #pragma unroll
        for (int j = 0; j < 8; ++j) acc[j] += w0.f * bf2f(v0[j]);
        #pragma unroll
        for (int j = 0; j < 8; ++j) acc[j] += w1.f * bf2f(v1[j]);
    }
    for (; e < end; e += 2) {
        uint2 cv = csr_cv[e];
        ushort8 v = *(const ushort8*)&xbf[(size_t)cv.x * 256 + hl * 8];
        union { unsigned u; float f; } w; w.u = cv.y;
        #pragma unroll
        for (int j = 0; j < 8; ++j) acc[j] += w.f * bf2f(v[j]);
    }
    #pragma unroll
    for (int j = 0; j < 8; ++j) acc[j] += __shfl_xor(acc[j], 32, 64);
    if (half == 0) {
        ushort8 o;
        #pragma unroll
        for (int j = 0; j < 8; ++j) o[j] = f2bf(acc[j]);
        *(ushort8*)&agg_bf[(size_t)row * 256 + hl * 8] = o;
    }
}

// ---- W fp32 -> bf16 ------------------------------------------------------
__global__ void wconv_kernel(const float* __restrict__ W, ushort* __restrict__ Wbf) {
    int i = blockIdx.x * 256 + threadIdx.x;
    Wbf[i] = f2bf(W[i]);
}

// ---- GEMM: out[i][n] = sum_k agg[i][k] * W[n][k] (bf16 MFMA) ------------
__global__ __launch_bounds__(256) void gemm_kernel(
        const ushort* __restrict__ Abf,   // [N][256] bf16
        const ushort* __restrict__ Wbf,   // [256][256] bf16, n-major (k contiguous)
        float* __restrict__ out) {        // [N][256] fp32
    int w    = threadIdx.x >> 6;
    int lane = threadIdx.x & 63;
    int quad = lane >> 4;
    int l16  = lane & 15;
    int rt   = blockIdx.x * 16;           // 6250 blocks

    float4v acc[4];
    #pragma unroll
    for (int i = 0; i < 4; ++i) acc[i] = (float4v){0.f, 0.f, 0.f, 0.f};

    #pragma unroll
    for (int k0 = 0; k0 < 256; k0 += 32) {
        short8 a = *(const short8*)&Abf[(rt + l16) * 256 + k0 + quad * 8];
        #pragma unroll
        for (int nt = 0; nt < 4; ++nt) {
            int n = w * 64 + nt * 16 + l16;
            short8 b = *(const short8*)&Wbf[n * 256 + k0 + quad * 8];
            acc[nt] = __builtin_amdgcn_mfma_f32_16x16x32_bf16(a, b, acc[nt], 0, 0, 0);
        }
    }
    #pragma unroll
    for (int nt = 0; nt < 4; ++nt) {
        int n = w * 64 + nt * 16 + l16;
        #pragma unroll
        for (int r = 0; r < 4; ++r) {
            int row = rt + quad * 4 + r;   // C/D: col=lane&15, row=quad*4+reg
            out[row * 256 + n] = acc[nt][r];
        }
    }
}

// ---- launch --------------------------------------------------------------

extern "C" void kernel_launch(void* const* d_in, const int* in_sizes, int n_in,
                              void* d_out, int out_size, void* d_ws, size_t ws_size,
                              hipStream_t stream) {
    const float* x    = (const float*)d_in[0];
    const int*   erow = (const int*)d_in[1];
    const int*   ecol = (const int*)d_in[2];
    const float* eval = (const float*)d_in[3];
    const float* W    = (const float*)d_in[4];
    float* out = (float*)d_out;

    char* ws = (char*)d_ws;
    size_t off = 0;
    int* row_start = (int*)(ws + off);   off += ((size_t)(N_NODES + 1) * 4 + 255) & ~255ull;
    int* cursor    = (int*)(ws + off);   off += ((size_t)N_NODES * 4 + 255) & ~255ull;
    int* bsum      = (int*)(ws + off);   off += ((size_t)NBLK * 4 + 255) & ~255ull;
    int* bbase     = (int*)(ws + off);   off += ((size_t)NBLK * 4 + 255) & ~255ull;
    uint2* csr_cv  = (uint2*)(ws + off); off += (size_t)N_EDGES * 8;
    ushort* Wbf    = (ushort*)(ws + off);  off += (size_t)D_FEAT * D_FEAT * 2;
    ushort* xbf    = (ushort*)(ws + off);  off += (size_t)N_NODES * D_FEAT * 2;
    ushort* agg_bf = (ushort*)(ws + off);  off += (size_t)N_NODES * D_FEAT * 2;

    hipMemsetAsync(row_start, 0, (N_NODES + 1) * sizeof(int), stream);
    xconv_kernel<<<(N_NODES * D_FEAT / 4) / 256, 256, 0, stream>>>((const float4*)x, (ushort4*)xbf);
    hist_kernel<<<N_EDGES / 256, 256, 0, stream>>>(erow, row_start);
    scan_pass1<<<NBLK, 256, 0, stream>>>(row_start, bsum);
    scan_pass2<<<1, 512, 0, stream>>>(bsum, bbase);
    scan_pass3<<<NBLK, 256, 0, stream>>>(row_start, bbase, row_start, cursor);
    scatter_kernel<<<N_EDGES / 256, 256, 0, stream>>>(erow, ecol, eval, cursor, csr_cv);
    wconv_kernel<<<(D_FEAT * D_FEAT) / 256, 256, 0, stream>>>(W, Wbf);
    spmm_kernel<<<(N_NODES + 3) / 4, 256, 0, stream>>>(xbf, row_start, csr_cv, agg_bf);
    gemm_kernel<<<N_NODES / 16, 256, 0, stream>>>(agg_bf, Wbf, out);
}

// Round 3
// 592.386 us; speedup vs baseline: 2.2323x; 1.5103x over previous
//
#include <hip/hip_runtime.h>
#include <hip/hip_bf16.h>
#include <stdint.h>

#define N_NODES 100000
#define N_EDGES 3200000
#define D_FEAT 256
#define NBKT 391      // ceil(N_NODES / 256) coarse buckets (row >> 8)
#define CHUNK 8192    // edges per coarse block
#define NBLK_E 391    // ceil(N_EDGES / CHUNK)

typedef __attribute__((ext_vector_type(8))) short short8;
typedef __attribute__((ext_vector_type(8))) ushort ushort8;
typedef __attribute__((ext_vector_type(4))) float float4v;

__device__ inline unsigned short f2bf(float f) {
    union { float f; unsigned u; } v; v.f = f;
    unsigned u = v.u;
    u += 0x7FFF + ((u >> 16) & 1);   // round-to-nearest-even
    return (unsigned short)(u >> 16);
}
__device__ inline float bf2f(unsigned short u) {
    union { unsigned u; float f; } v; v.u = (unsigned)u << 16;
    return v.f;
}

// ---- x fp32 -> bf16 (streaming) -----------------------------------------
__global__ __launch_bounds__(256) void xconv_kernel(const float4* __restrict__ x4,
                                                    ushort4* __restrict__ xbf4) {
    int i = blockIdx.x * 256 + threadIdx.x;   // 25000 blocks, exact
    float4 v = x4[i];
    ushort4 o;
    o.x = f2bf(v.x); o.y = f2bf(v.y); o.z = f2bf(v.z); o.w = f2bf(v.w);
    xbf4[i] = o;
}

// ---- CSR build: two-level LDS counting sort -----------------------------

// A: per-chunk coarse histogram (LDS atomics only)
__global__ __launch_bounds__(256) void coarse_hist(const int* __restrict__ erow,
                                                   int* __restrict__ hist) {
    __shared__ int cnt[NBKT];
    for (int b = threadIdx.x; b < NBKT; b += 256) cnt[b] = 0;
    __syncthreads();
    int cb = blockIdx.x * CHUNK;
    for (int j = 0; j < CHUNK; j += 256) {
        int i = cb + j + threadIdx.x;
        if (i < N_EDGES) atomicAdd(&cnt[erow[i] >> 8], 1);
    }
    __syncthreads();
    for (int b = threadIdx.x; b < NBKT; b += 256)
        hist[blockIdx.x * NBKT + b] = cnt[b];
}

// B1: per-bucket exclusive scan over chunk-blocks (in-place), emit totals
__global__ __launch_bounds__(512) void scan_blocks(int* __restrict__ hist,
                                                   int* __restrict__ totals) {
    __shared__ int s[512];
    int b = blockIdx.x;          // bucket
    int t = threadIdx.x;
    int v = (t < NBLK_E) ? hist[t * NBKT + b] : 0;
    s[t] = v;
    __syncthreads();
    for (int o = 1; o < 512; o <<= 1) {
        int x = (t >= o) ? s[t - o] : 0;
        __syncthreads();
        s[t] += x;
        __syncthreads();
    }
    if (t < NBLK_E) hist[t * NBKT + b] = s[t] - v;   // exclusive within bucket
    if (t == NBLK_E - 1) totals[b] = s[t];
}

// B2: exclusive scan of bucket totals -> bucket bases
__global__ __launch_bounds__(512) void scan_buckets(const int* __restrict__ totals,
                                                    int* __restrict__ base_,
                                                    int* __restrict__ row_start) {
    __shared__ int s[512];
    int t = threadIdx.x;
    int v = (t < NBKT) ? totals[t] : 0;
    s[t] = v;
    __syncthreads();
    for (int o = 1; o < 512; o <<= 1) {
        int x = (t >= o) ? s[t - o] : 0;
        __syncthreads();
        s[t] += x;
        __syncthreads();
    }
    if (t < NBKT) base_[t] = s[t] - v;
    if (t == 0) { base_[NBKT] = N_EDGES; row_start[N_NODES] = N_EDGES; }
}

// C: coarse scatter into bucket-ordered tmp (LDS cursors, semi-coalesced writes)
__global__ __launch_bounds__(256) void coarse_scatter(
        const int* __restrict__ erow, const int* __restrict__ ecol,
        const float* __restrict__ eval,
        const int* __restrict__ hist, const int* __restrict__ base_,
        uint2* __restrict__ tmp) {
    __shared__ int lbase[NBKT];
    __shared__ int cnt[NBKT];
    for (int b = threadIdx.x; b < NBKT; b += 256) {
        lbase[b] = hist[blockIdx.x * NBKT + b] + base_[b];
        cnt[b] = 0;
    }
    __syncthreads();
    int cb = blockIdx.x * CHUNK;
    for (int j = 0; j < CHUNK; j += 256) {
        int i = cb + j + threadIdx.x;
        if (i < N_EDGES) {
            int r = erow[i];
            int b = r >> 8;
            int pos = lbase[b] + atomicAdd(&cnt[b], 1);
            uint2 cv;
            cv.x = (unsigned)ecol[i] | ((unsigned)(r & 255) << 17);  // col<2^17
            union { float f; unsigned u; } w; w.f = eval[i];
            cv.y = w.u;
            tmp[pos] = cv;
        }
    }
}

// D: fine counting sort within each bucket; writes final CSR + row_start
__global__ __launch_bounds__(256) void fine_sort(const uint2* __restrict__ tmp,
                                                 const int* __restrict__ base_,
                                                 uint2* __restrict__ csr,
                                                 int* __restrict__ row_start) {
    __shared__ int cnt[256];
    __shared__ int excl[256];
    int b = blockIdx.x;
    int t = threadIdx.x;
    int s0 = base_[b];
    int nb = base_[b + 1] - s0;
    cnt[t] = 0;
    __syncthreads();
    for (int j = t; j < nb; j += 256)
        atomicAdd(&cnt[tmp[s0 + j].x >> 17], 1);
    __syncthreads();
    int v = cnt[t];
    excl[t] = v;
    __syncthreads();
    for (int o = 1; o < 256; o <<= 1) {
        int x = (t >= o) ? excl[t - o] : 0;
        __syncthreads();
        excl[t] += x;
        __syncthreads();
    }
    int ex = excl[t] - v;            // exclusive prefix for row_low == t
    int row = b * 256 + t;
    if (row < N_NODES) row_start[row] = s0 + ex;
    excl[t] = ex;                    // own-slot overwrite, safe
    cnt[t] = 0;                      // reuse as cursor
    __syncthreads();
    for (int j = t; j < nb; j += 256) {
        uint2 cv = tmp[s0 + j];
        unsigned rl = cv.x >> 17;
        int dst = s0 + excl[rl] + atomicAdd(&cnt[rl], 1);
        csr[dst] = cv;
    }
}

// ---- SpMM: one wave per row, half-wave per edge -------------------------
__global__ __launch_bounds__(256) void spmm_kernel(
        const ushort* __restrict__ xbf,           // [N][256] bf16
        const int* __restrict__ row_start,
        const uint2* __restrict__ csr_cv,         // col in low 17 bits of .x
        ushort* __restrict__ agg_bf) {            // [N][256] bf16
    int row  = (blockIdx.x * blockDim.x + threadIdx.x) >> 6;
    int lane = threadIdx.x & 63;
    int half = lane >> 5;
    int hl   = lane & 31;
    if (row >= N_NODES) return;
    int start = row_start[row];
    int end   = row_start[row + 1];
    float acc[8] = {0.f, 0.f, 0.f, 0.f, 0.f, 0.f, 0.f, 0.f};
    int e = start + half;
    for (; e + 2 < end; e += 4) {
        uint2 cv0 = csr_cv[e];
        uint2 cv1 = csr_cv[e + 2];
        ushort8 v0 = *(const ushort8*)&xbf[(size_t)(cv0.x & 0x1FFFF) * 256 + hl * 8];
        ushort8 v1 = *(const ushort8*)&xbf[(size_t)(cv1.x & 0x1FFFF) * 256 + hl * 8];
        union { unsigned u; float f; } w0, w1;
        w0.u = cv0.y; w1.u = cv1.y;
        #pragma unroll
        for (int j = 0; j < 8; ++j) acc[j] += w0.f * bf2f(v0[j]);
        #pragma unroll
        for (int j = 0; j < 8; ++j) acc[j] += w1.f * bf2f(v1[j]);
    }
    for (; e < end; e += 2) {
        uint2 cv = csr_cv[e];
        ushort8 v = *(const ushort8*)&xbf[(size_t)(cv.x & 0x1FFFF) * 256 + hl * 8];
        union { unsigned u; float f; } w; w.u = cv.y;
        #pragma unroll
        for (int j = 0; j < 8; ++j) acc[j] += w.f * bf2f(v[j]);
    }
    #pragma unroll
    for (int j = 0; j < 8; ++j) acc[j] += __shfl_xor(acc[j], 32, 64);
    if (half == 0) {
        ushort8 o;
        #pragma unroll
        for (int j = 0; j < 8; ++j) o[j] = f2bf(acc[j]);
        *(ushort8*)&agg_bf[(size_t)row * 256 + hl * 8] = o;
    }
}

// ---- W fp32 -> bf16 ------------------------------------------------------
__global__ void wconv_kernel(const float* __restrict__ W, ushort* __restrict__ Wbf) {
    int i = blockIdx.x * 256 + threadIdx.x;
    Wbf[i] = f2bf(W[i]);
}

// ---- GEMM: 64 rows/block, 4x W reuse per wave ---------------------------
__global__ __launch_bounds__(256) void gemm_kernel(
        const ushort* __restrict__ Abf,   // [N][256] bf16
        const ushort* __restrict__ Wbf,   // [256][256] bf16, n-major
        float* __restrict__ out) {        // [N][256] fp32
    int w    = threadIdx.x >> 6;
    int lane = threadIdx.x & 63;
    int quad = lane >> 4;
    int l16  = lane & 15;
    int rt   = blockIdx.x * 64;           // 1563 blocks

    float4v acc[4][4];
    #pragma unroll
    for (int mt = 0; mt < 4; ++mt)
        #pragma unroll
        for (int nt = 0; nt < 4; ++nt) acc[mt][nt] = (float4v){0.f, 0.f, 0.f, 0.f};

    #pragma unroll
    for (int k0 = 0; k0 < 256; k0 += 32) {
        short8 a[4], bf[4];
        #pragma unroll
        for (int mt = 0; mt < 4; ++mt) {
            int row = rt + mt * 16 + l16;
            if (row >= N_NODES) row = N_NODES - 1;   // clamp (tail block)
            a[mt] = *(const short8*)&Abf[(size_t)row * 256 + k0 + quad * 8];
        }
        #pragma unroll
        for (int nt = 0; nt < 4; ++nt) {
            int n = w * 64 + nt * 16 + l16;
            bf[nt] = *(const short8*)&Wbf[n * 256 + k0 + quad * 8];
        }
        #pragma unroll
        for (int mt = 0; mt < 4; ++mt)
            #pragma unroll
            for (int nt = 0; nt < 4; ++nt)
                acc[mt][nt] = __builtin_amdgcn_mfma_f32_16x16x32_bf16(a[mt], bf[nt], acc[mt][nt], 0, 0, 0);
    }
    #pragma unroll
    for (int mt = 0; mt < 4; ++mt)
        #pragma unroll
        for (int nt = 0; nt < 4; ++nt) {
            int n = w * 64 + nt * 16 + l16;
            #pragma unroll
            for (int r = 0; r < 4; ++r) {
                int row = rt + mt * 16 + quad * 4 + r;   // C/D: col=lane&15, row=quad*4+reg
                if (row < N_NODES) out[(size_t)row * 256 + n] = acc[mt][nt][r];
            }
        }
}

// ---- launch --------------------------------------------------------------

extern "C" void kernel_launch(void* const* d_in, const int* in_sizes, int n_in,
                              void* d_out, int out_size, void* d_ws, size_t ws_size,
                              hipStream_t stream) {
    const float* x    = (const float*)d_in[0];
    const int*   erow = (const int*)d_in[1];
    const int*   ecol = (const int*)d_in[2];
    const float* eval = (const float*)d_in[3];
    const float* W    = (const float*)d_in[4];
    float* out = (float*)d_out;

    char* ws = (char*)d_ws;
    size_t off = 0;
    int* hist      = (int*)(ws + off);   off += ((size_t)NBLK_E * NBKT * 4 + 255) & ~255ull;
    int* totals    = (int*)(ws + off);   off += ((size_t)NBKT * 4 + 255) & ~255ull;
    int* base_     = (int*)(ws + off);   off += ((size_t)(NBKT + 1) * 4 + 255) & ~255ull;
    int* row_start = (int*)(ws + off);   off += ((size_t)(N_NODES + 1) * 4 + 255) & ~255ull;
    uint2* tmp_cv  = (uint2*)(ws + off); off += (size_t)N_EDGES * 8;
    uint2* csr_cv  = (uint2*)(ws + off); off += (size_t)N_EDGES * 8;
    ushort* Wbf    = (ushort*)(ws + off);  off += (size_t)D_FEAT * D_FEAT * 2;
    ushort* xbf    = (ushort*)(ws + off);  off += (size_t)N_NODES * D_FEAT * 2;
    ushort* agg_bf = (ushort*)(ws + off);  off += (size_t)N_NODES * D_FEAT * 2;

    xconv_kernel<<<(N_NODES * D_FEAT / 4) / 256, 256, 0, stream>>>((const float4*)x, (ushort4*)xbf);
    coarse_hist<<<NBLK_E, 256, 0, stream>>>(erow, hist);
    scan_blocks<<<NBKT, 512, 0, stream>>>(hist, totals);
    scan_buckets<<<1, 512, 0, stream>>>(totals, base_, row_start);
    coarse_scatter<<<NBLK_E, 256, 0, stream>>>(erow, ecol, eval, hist, base_, tmp_cv);
    fine_sort<<<NBKT, 256, 0, stream>>>(tmp_cv, base_, csr_cv, row_start);
    wconv_kernel<<<(D_FEAT * D_FEAT) / 256, 256, 0, stream>>>(W, Wbf);
    spmm_kernel<<<N_NODES / 4, 256, 0, stream>>>(xbf, row_start, csr_cv, agg_bf);
    gemm_kernel<<<(N_NODES + 63) / 64, 256, 0, stream>>>(agg_bf, Wbf, out);
}